// Round 5
// baseline (282.922 us; speedup 1.0000x reference)
//
#include <hip/hip_runtime.h>
#include <hip/hip_bf16.h>

// B=4, T=2048, H=1024, NH=16, HD=64. Inputs FP32, output FP32.
// R14: GEMM inner-loop fixes (attn untouched):
//  [a] frag-read swizzle corrected to f(row)=(row>>1)&3 (was row&3):
//      bank-quad occupancy now uniform 8 lanes/quad (intrinsic minimum)
//      -> kills the residual 4-way conflict (6.29M cyc, 13.6% of runtime).
//  [b] 3-buffer staging pipeline with counted vmcnt: stage(t+2) issued each
//      iter; before the (raw) barrier only `s_waitcnt vmcnt(4)` -- the
//      t+1 slab must land, the t+2 slab stays in flight across the barrier
//      (T4). Each slab now has TWO MFMA phases of latency cover, vs the
//      __syncthreads vmcnt(0) drain that exposed it every step.

typedef unsigned short ushort_t;
typedef __attribute__((ext_vector_type(8))) short  s8v;
typedef __attribute__((ext_vector_type(4))) float  f4v;
typedef __attribute__((ext_vector_type(4))) unsigned int u4v;

__device__ inline ushort_t f2bf(float f) {
    unsigned u = __builtin_bit_cast(unsigned, f);
    u += 0x7fffu + ((u >> 16) & 1u);   // RNE
    return (ushort_t)(u >> 16);
}

// async global->LDS, 16B per lane; LDS dest must be wave-uniform base + lane*16
__device__ inline void gload16(const ushort_t* g, ushort_t* l) {
    __builtin_amdgcn_global_load_lds(
        (const __attribute__((address_space(1))) unsigned int*)g,
        (__attribute__((address_space(3))) unsigned int*)l, 16, 0, 0);
}

__global__ __launch_bounds__(256) void cast_f32_bf16(
    const float* __restrict__ in, ushort_t* __restrict__ out, int n8)
{
    int i = blockIdx.x * 256 + threadIdx.x;
    if (i >= n8) return;
    const float* p = in + (size_t)i * 8;
    f4v a = *(const f4v*)p;
    f4v b = *(const f4v*)(p + 4);
    union { u4v v; ushort_t u[8]; } o;
    #pragma unroll
    for (int j = 0; j < 4; j++) { o.u[j] = f2bf(a[j]); o.u[j + 4] = f2bf(b[j]); }
    *(u4v*)(out + (size_t)i * 8) = o.v;
}

// ---------------------------------------------------------------------------
// V transpose: in [bh][2048][64] (t-major) -> out [bh][64][2048] (d-major),
// with keys sigma-permuted within each 64-block to match the packed P layout:
// sigma position s -> key k = (s>>5)*32 + (s&1)*16 + ((s&31)>>1).
// ---------------------------------------------------------------------------
__global__ __launch_bounds__(256) void transpose_v(
    const ushort_t* __restrict__ in, ushort_t* __restrict__ out)
{
    const int t0 = blockIdx.x * 64;
    const int bh = blockIdx.y;
    const ushort_t* src = in  + ((size_t)bh * 2048 + t0) * 64;
    ushort_t*       dst = out + (size_t)bh * 64 * 2048 + t0;
    __shared__ __align__(16) ushort_t L[64 * 72];   // [t][72]
    const int tid = threadIdx.x;

    #pragma unroll
    for (int j = 0; j < 2; j++) {
        int c = tid + j * 256;            // 0..511
        int t = c >> 3, d0 = (c & 7) * 8;
        *(s8v*)&L[t * 72 + d0] = *(const s8v*)(src + (size_t)t * 64 + d0);
    }
    __syncthreads();
    #pragma unroll
    for (int j = 0; j < 2; j++) {
        int c = tid + j * 256;
        int d = c >> 3, sp0 = (c & 7) * 8;
        union { s8v v; ushort_t u[8]; } o;
        #pragma unroll
        for (int i = 0; i < 8; i++) {
            int sp = sp0 + i;             // sigma position 0..63
            int sl = sp & 31;
            int k  = (sp >> 5) * 32 + (sl & 1) * 16 + (sl >> 1);
            o.u[i] = L[k * 72 + d];
        }
        *(s8v*)(dst + (size_t)d * 2048 + sp0) = o.v;
    }
}

// ---------------------------------------------------------------------------
// GEMM C[M,N] = A[M,K]*B[N,K]^T, K=1024, bf16 MFMA, f32 acc.
// BM=BN=128, BK=32, global_load_lds width 16, XOR chunk swizzle (row>>1)&3.
// 3-buffer LDS pipeline, counted vmcnt(4) + raw s_barrier per K-step.
// MODE 0: scatter q/k/v (bf16; V t-major); Q scaled by 0.125*log2e.
// MODE 1: row-major FP32 store.
// ---------------------------------------------------------------------------
template<int MODE>
__global__ __launch_bounds__(256) void gemm_nt(
    const ushort_t* __restrict__ A, const ushort_t* __restrict__ Bm,
    ushort_t* __restrict__ o0, ushort_t* __restrict__ o1, ushort_t* __restrict__ o2,
    float* __restrict__ of)
{
    __shared__ __align__(16) ushort_t As[3][4096];   // [buf][128][32], chunk-swz
    __shared__ __align__(16) ushort_t Bs[3][4096];

    const int tid  = threadIdx.x;
    const int m0   = blockIdx.x * 128;
    const int n0   = blockIdx.y * 128;
    const int wave = tid >> 6, lane = tid & 63;
    const int wr = wave >> 1, wc = wave & 1;
    const int lhi = lane >> 4, llo = lane & 15;
    const int srow = lane >> 2;
    // phys chunk (lane&3) holds logical chunk (lane&3)^((srow>>1)&3)
    const int scol = (((lane & 3) ^ ((srow >> 1) & 3)) * 8);

    auto stage = [&](int k0, int buf) {
        #pragma unroll
        for (int p = 0; p < 2; p++) {
            int chunk = wave * 2 + p;                     // 0..7, 16 rows each
            int row = chunk * 16 + srow;
            gload16(A  + (size_t)(m0 + row) * 1024 + k0 + scol,
                    &As[buf][chunk * 512 + lane * 8]);
            gload16(Bm + (size_t)(n0 + row) * 1024 + k0 + scol,
                    &Bs[buf][chunk * 512 + lane * 8]);
        }
    };

    f4v acc[4][4] = {};

    stage(0, 0);                           // 4 loads
    stage(32, 1);                          // 4 loads (8 outstanding)
    asm volatile("s_waitcnt vmcnt(4)" ::: "memory");   // slab 0 landed
    __builtin_amdgcn_s_barrier();

    int buf = 0;
    for (int k0 = 0; k0 < 1024; k0 += 32) {
        const bool pf = (k0 + 64 < 1024);
        if (pf) {
            int nb = buf + 2; if (nb >= 3) nb -= 3;
            stage(k0 + 64, nb);            // slab t+2: 2 phases to land
        }

        // row = wr*64 + i*16 + llo -> (row>>1)&3 == (llo>>1)&3
        const int rch = (lhi ^ ((llo >> 1) & 3)) * 8;
        s8v a[4], b[4];
        #pragma unroll
        for (int i = 0; i < 4; i++)
            a[i] = *(const s8v*)&As[buf][(wr * 64 + i * 16 + llo) * 32 + rch];
        #pragma unroll
        for (int i = 0; i < 4; i++)
            b[i] = *(const s8v*)&Bs[buf][(wc * 64 + i * 16 + llo) * 32 + rch];
        #pragma unroll
        for (int i = 0; i < 4; i++)
            #pragma unroll
            for (int j = 0; j < 4; j++)
                acc[i][j] = __builtin_amdgcn_mfma_f32_16x16x32_bf16(a[i], b[j], acc[i][j], 0, 0, 0);

        if (k0 + 32 < 1024) {              // next iteration exists
            if (pf) asm volatile("s_waitcnt vmcnt(4)" ::: "memory");  // t+1 done
            else    asm volatile("s_waitcnt vmcnt(0)" ::: "memory");  // last slab
            __builtin_amdgcn_s_barrier();
        }
        buf = (buf == 2) ? 0 : buf + 1;
    }

    #pragma unroll
    for (int i = 0; i < 4; i++) {
        #pragma unroll
        for (int j = 0; j < 4; j++) {
            #pragma unroll
            for (int r = 0; r < 4; r++) {
                int m = m0 + wr * 64 + i * 16 + lhi * 4 + r;
                int n = n0 + wc * 64 + j * 16 + llo;
                if (MODE == 1) {
                    of[(size_t)m * 1024 + n] = acc[i][j][r];
                } else {
                    float val = acc[i][j][r];
                    int b  = m >> 11, t = m & 2047;
                    int which = n >> 10, hh = n & 1023;
                    int head = hh >> 6, d = hh & 63;
                    size_t bh = (size_t)(b * 16 + head);
                    if (which == 0)
                        // Q [b*T+t][h*64+d], pre-scaled by 1/sqrt(64)*log2(e)
                        o0[(size_t)m * 1024 + hh] = f2bf(val * 0.18033688011112042f);
                    else {
                        // K and V both t-major [b,h,t,d] (coalesced);
                        // V transposed+sigma-permuted later by transpose_v.
                        ushort_t* dst = (which == 1) ? o1 : o2;
                        dst[(bh * 2048 + t) * 64 + d] = f2bf(val);
                    }
                }
            }
        }
    }
}

// ---------------------------------------------------------------------------
// Flash attention, causal, exp2 domain, m-free softmax.
// Block: waves 0-3 -> q-tile p, waves 4-7 -> q-tile 15-p (32 rows/wave as
// 2 x 16-row groups). Shared KV loop of 32-2p tiles; K/V staged once for
// both q-tiles. KV tile 64 keys, double-buffered; 1 barrier/tile.
// K/V LDS: [64 rows][64 cols], 16B chunks XOR-swizzled by (row&7).
// P stored sigma-packed: col = llo*2+(c&1) per 32-half, matching sigma-
// permuted V^T; stores are ds_write_b32 of v_cvt_pk_bf16_f32 pairs.
// ---------------------------------------------------------------------------
__global__ __launch_bounds__(512, 4) void attn_kernel(
    const ushort_t* __restrict__ q_ws, const ushort_t* __restrict__ k_ws,
    const ushort_t* __restrict__ v_ws, ushort_t* __restrict__ ao_ws)
{
    const int p    = blockIdx.x;          // 0..7 -> q-tiles (p, 15-p)
    const int bh   = blockIdx.y;
    const int tid  = threadIdx.x;
    const int wave = tid >> 6, lane = tid & 63;
    const int lhi = lane >> 4, llo = lane & 15;
    const int b = bh >> 4, head = bh & 15;

    const ushort_t* Kb = k_ws + (size_t)bh * 2048 * 64;
    const ushort_t* Vb = v_ws + (size_t)bh * 64 * 2048;   // [d][sigma(t)]

    __shared__ __align__(16) ushort_t Ks [2][4096];       // [buf][64 kk][64 d] swz
    __shared__ __align__(16) ushort_t Vts[2][4096];       // [buf][64 d][64 sig] swz
    __shared__ __align__(16) ushort_t Ps [8][2][1280];    // [wave][g][half][16q][40]

    // stage tile t (64 keys, K+V) into buffer buf; 1 K + 1 V chunk per lane.
    const int srow = wave * 8 + (lane >> 3);              // 0..63
    const int gch  = ((lane & 7) ^ (srow & 7)) * 8;       // pre-swizzled src col
    auto stage = [&](int t, int buf) {
        const int kk0 = t * 64;
        gload16(Kb + (size_t)(kk0 + srow) * 64 + gch,
                &Ks[buf][srow * 64 + (lane & 7) * 8]);
        gload16(Vb + (size_t)srow * 2048 + kk0 + gch,
                &Vts[buf][srow * 64 + (lane & 7) * 8]);
    };

    const int qt  = (wave >> 2) ? (15 - p) : p;           // this wave's q-tile
    const int wq0 = qt * 128 + (wave & 3) * 32;           // wave's 32 q-rows

    s8v qf[2][2];
    #pragma unroll
    for (int g = 0; g < 2; g++) {
        const ushort_t* Qp = q_ws + (size_t)(b * 2048 + wq0 + g * 16 + llo) * 1024 + head * 64;
        qf[g][0] = *(const s8v*)(Qp + lhi * 8);
        qf[g][1] = *(const s8v*)(Qp + 32 + lhi * 8);
    }

    f4v o[2][4] = {};
    float lsum[2][4] = {};

    const int ntb = 32 - 2 * p;           // shared loop length (tile 15-p range)
    const int xs  = llo & 7;              // read-side XOR (row&7 == llo&7)
    int cur = 0;

    stage(0, 0);
    __syncthreads();                      // tile 0 staged (drains vmcnt)

    #pragma unroll 1
    for (int t = 0; t < ntb; t++) {
        if (t + 1 < ntb) stage(t + 1, cur ^ 1);   // prefetch next tile

        const int kk0 = t * 64;
        // kk0 multiple of 64, wq0 multiple of 32 => if any row unmasked,
        // BOTH 16-row groups have unmasked rows.
        if (kk0 <= wq0 + 31) {
            // ---- QK^T for both groups; kb frags transient per c ----
            f4v s0[4], s1[4];
            #pragma unroll
            for (int c = 0; c < 4; c++) {
                const int rb = (c * 16 + llo) * 64;
                s8v kb0 = *(const s8v*)&Ks[cur][rb + ((lhi    ) ^ xs) * 8];
                s8v kb1 = *(const s8v*)&Ks[cur][rb + ((4 + lhi) ^ xs) * 8];
                f4v z0 = {}, z1 = {};
                z0 = __builtin_amdgcn_mfma_f32_16x16x32_bf16(qf[0][0], kb0, z0, 0, 0, 0);
                z0 = __builtin_amdgcn_mfma_f32_16x16x32_bf16(qf[0][1], kb1, z0, 0, 0, 0);
                z1 = __builtin_amdgcn_mfma_f32_16x16x32_bf16(qf[1][0], kb0, z1, 0, 0, 0);
                z1 = __builtin_amdgcn_mfma_f32_16x16x32_bf16(qf[1][1], kb1, z1, 0, 0, 0);
                s0[c] = z0; s1[c] = z1;
            }

            // ---- m-free softmax + sigma-packed P store, per group ----
            #pragma unroll
            for (int g = 0; g < 2; g++) {
                const int qrb = wq0 + g * 16;
                f4v* s = g ? s1 : s0;
                if ((kk0 + 63) > qrb) {               // boundary: apply mask
                    #pragma unroll
                    for (int c = 0; c < 4; c++) {
                        int kkg = kk0 + c * 16 + llo;
                        #pragma unroll
                        for (int r = 0; r < 4; r++)
                            if (kkg > qrb + lhi * 4 + r) s[c][r] = -1e9f;
                    }
                }
                #pragma unroll
                for (int h = 0; h < 2; h++) {
                    #pragma unroll
                    for (int r = 0; r < 4; r++) {
                        float p0 = __builtin_amdgcn_exp2f(s[2 * h][r]);
                        float p1 = __builtin_amdgcn_exp2f(s[2 * h + 1][r]);
                        lsum[g][r] += p0 + p1;
                        unsigned pk;
                        asm("v_cvt_pk_bf16_f32 %0, %1, %2" : "=v"(pk) : "v"(p0), "v"(p1));
                        *(unsigned*)&Ps[wave][g][h * 640 + (lhi * 4 + r) * 40 + llo * 2] = pk;
                    }
                }
            }

            // ---- PV for both groups; vb frags transient per cd ----
            s8v pa[2][2];
            #pragma unroll
            for (int g = 0; g < 2; g++) {
                pa[g][0] = *(const s8v*)&Ps[wave][g][llo * 40 + lhi * 8];
                pa[g][1] = *(const s8v*)&Ps[wave][g][640 + llo * 40 + lhi * 8];
            }
            #pragma unroll
            for (int cd = 0; cd < 4; cd++) {
                const int rb = (cd * 16 + llo) * 64;
                s8v vb0 = *(const s8v*)&Vts[cur][rb + ((lhi    ) ^ xs) * 8];
                s8v vb1 = *(const s8v*)&Vts[cur][rb + ((4 + lhi) ^ xs) * 8];
                #pragma unroll
                for (int g = 0; g < 2; g++) {
                    o[g][cd] = __builtin_amdgcn_mfma_f32_16x16x32_bf16(pa[g][0], vb0, o[g][cd], 0, 0, 0);
                    o[g][cd] = __builtin_amdgcn_mfma_f32_16x16x32_bf16(pa[g][1], vb1, o[g][cd], 0, 0, 0);
                }
            }
        }

        __syncthreads();   // all waves done with buf cur; prefetch complete
        cur ^= 1;
    }

    // final l-sum reduction across the 16-lane llo group
    #pragma unroll
    for (int off = 1; off < 16; off <<= 1)
        #pragma unroll
        for (int g = 0; g < 2; g++)
            #pragma unroll
            for (int r = 0; r < 4; r++)
                lsum[g][r] += __shfl_xor(lsum[g][r], off, 64);

    #pragma unroll
    for (int g = 0; g < 2; g++)
        #pragma unroll
        for (int cd = 0; cd < 4; cd++)
            #pragma unroll
            for (int r = 0; r < 4; r++) {
                int qq = wq0 + g * 16 + lhi * 4 + r;
                int d  = cd * 16 + llo;
                ao_ws[((size_t)(b * 2048 + qq)) * 1024 + head * 64 + d] =
                    f2bf(o[g][cd][r] / lsum[g][r]);
            }
}

// ---------------------------------------------------------------------------
extern "C" void kernel_launch(void* const* d_in, const int* in_sizes, int n_in,
                              void* d_out, int out_size, void* d_ws, size_t ws_size,
                              hipStream_t stream) {
    const float* x    = (const float*)d_in[0];
    const float* wqkv = (const float*)d_in[1];
    const float* wout = (const float*)d_in[2];

    // ws (bf16 elems): wqkvb 3M | woutb 1M | xb 8M | q 8M | k 8M | vt 8M = 72 MB
    // reuse: v^T <- xb (dead after gemm0); ao <- vt (dead after transpose)
    ushort_t* wqkvb = (ushort_t*)d_ws;
    ushort_t* woutb = wqkvb + 3145728;
    ushort_t* xb    = woutb + 1048576;
    ushort_t* q_ws  = xb + 8388608;
    ushort_t* k_ws  = q_ws + 8388608;
    ushort_t* vt_ws = k_ws + 8388608;     // V t-major [b,h,t,d] from gemm0
    ushort_t* v_ws  = xb;                 // V^T [b,h,d,sigma(t)]
    ushort_t* ao_ws = vt_ws;              // attn output
    float*    out   = (float*)d_out;

    cast_f32_bf16<<<4096, 256, 0, stream>>>(x,    xb,    1048576);
    cast_f32_bf16<<<1536, 256, 0, stream>>>(wqkv, wqkvb, 393216);
    cast_f32_bf16<<< 512, 256, 0, stream>>>(wout, woutb, 131072);
    gemm_nt<0><<<dim3(64, 24), 256, 0, stream>>>(xb, wqkvb, q_ws, k_ws, vt_ws, nullptr);
    transpose_v<<<dim3(32, 64), 256, 0, stream>>>(vt_ws, v_ws);
    attn_kernel<<<dim3(8, 64), 512, 0, stream>>>(q_ws, k_ws, v_ws, ao_ws);
    gemm_nt<1><<<dim3(64, 8), 256, 0, stream>>>(ao_ws, woutb, nullptr, nullptr, nullptr, out);
}

// Round 6
// 248.218 us; speedup vs baseline: 1.1398x; 1.1398x over previous
//
#include <hip/hip_runtime.h>
#include <hip/hip_bf16.h>

// B=4, T=2048, H=1024, NH=16, HD=64. Inputs FP32, output FP32.
// R15: GEMM = R4 structure + R5's conflict-free swizzle (keep ONLY the win):
//  - 2-buffer ping-pong (static buf^1, compiler unrolls x2), __syncthreads
//    per K-step. VGPR ~72, LDS 32KB, occupancy ~30% (R5's 3-buffer rotated
//    runtime index cost VALU addressing + occupancy: 21%, 39% VALU -> revert).
//  - frag swizzle f(row)=(row>>1)&3 on stage+read (R5-verified: conflicts=0).
// Attn / casts / transpose unchanged.

typedef unsigned short ushort_t;
typedef __attribute__((ext_vector_type(8))) short  s8v;
typedef __attribute__((ext_vector_type(4))) float  f4v;
typedef __attribute__((ext_vector_type(4))) unsigned int u4v;

__device__ inline ushort_t f2bf(float f) {
    unsigned u = __builtin_bit_cast(unsigned, f);
    u += 0x7fffu + ((u >> 16) & 1u);   // RNE
    return (ushort_t)(u >> 16);
}

// async global->LDS, 16B per lane; LDS dest must be wave-uniform base + lane*16
__device__ inline void gload16(const ushort_t* g, ushort_t* l) {
    __builtin_amdgcn_global_load_lds(
        (const __attribute__((address_space(1))) unsigned int*)g,
        (__attribute__((address_space(3))) unsigned int*)l, 16, 0, 0);
}

__global__ __launch_bounds__(256) void cast_f32_bf16(
    const float* __restrict__ in, ushort_t* __restrict__ out, int n8)
{
    int i = blockIdx.x * 256 + threadIdx.x;
    if (i >= n8) return;
    const float* p = in + (size_t)i * 8;
    f4v a = *(const f4v*)p;
    f4v b = *(const f4v*)(p + 4);
    union { u4v v; ushort_t u[8]; } o;
    #pragma unroll
    for (int j = 0; j < 4; j++) { o.u[j] = f2bf(a[j]); o.u[j + 4] = f2bf(b[j]); }
    *(u4v*)(out + (size_t)i * 8) = o.v;
}

// ---------------------------------------------------------------------------
// V transpose: in [bh][2048][64] (t-major) -> out [bh][64][2048] (d-major),
// with keys sigma-permuted within each 64-block to match the packed P layout:
// sigma position s -> key k = (s>>5)*32 + (s&1)*16 + ((s&31)>>1).
// ---------------------------------------------------------------------------
__global__ __launch_bounds__(256) void transpose_v(
    const ushort_t* __restrict__ in, ushort_t* __restrict__ out)
{
    const int t0 = blockIdx.x * 64;
    const int bh = blockIdx.y;
    const ushort_t* src = in  + ((size_t)bh * 2048 + t0) * 64;
    ushort_t*       dst = out + (size_t)bh * 64 * 2048 + t0;
    __shared__ __align__(16) ushort_t L[64 * 72];   // [t][72]
    const int tid = threadIdx.x;

    #pragma unroll
    for (int j = 0; j < 2; j++) {
        int c = tid + j * 256;            // 0..511
        int t = c >> 3, d0 = (c & 7) * 8;
        *(s8v*)&L[t * 72 + d0] = *(const s8v*)(src + (size_t)t * 64 + d0);
    }
    __syncthreads();
    #pragma unroll
    for (int j = 0; j < 2; j++) {
        int c = tid + j * 256;
        int d = c >> 3, sp0 = (c & 7) * 8;
        union { s8v v; ushort_t u[8]; } o;
        #pragma unroll
        for (int i = 0; i < 8; i++) {
            int sp = sp0 + i;             // sigma position 0..63
            int sl = sp & 31;
            int k  = (sp >> 5) * 32 + (sl & 1) * 16 + (sl >> 1);
            o.u[i] = L[k * 72 + d];
        }
        *(s8v*)(dst + (size_t)d * 2048 + sp0) = o.v;
    }
}

// ---------------------------------------------------------------------------
// GEMM C[M,N] = A[M,K]*B[N,K]^T, K=1024, bf16 MFMA, f32 acc.
// BM=BN=128, BK=32, global_load_lds width 16, XOR chunk swizzle (row>>1)&3.
// 2-buffer LDS ping-pong, prefetch next slab during MFMA, 1 barrier/K-step.
// MODE 0: scatter q/k/v (bf16; V t-major); Q scaled by 0.125*log2e.
// MODE 1: row-major FP32 store.
// ---------------------------------------------------------------------------
template<int MODE>
__global__ __launch_bounds__(256) void gemm_nt(
    const ushort_t* __restrict__ A, const ushort_t* __restrict__ Bm,
    ushort_t* __restrict__ o0, ushort_t* __restrict__ o1, ushort_t* __restrict__ o2,
    float* __restrict__ of)
{
    __shared__ __align__(16) ushort_t As[2][4096];   // [buf][128][32], chunk-swz
    __shared__ __align__(16) ushort_t Bs[2][4096];

    const int tid  = threadIdx.x;
    const int m0   = blockIdx.x * 128;
    const int n0   = blockIdx.y * 128;
    const int wave = tid >> 6, lane = tid & 63;
    const int wr = wave >> 1, wc = wave & 1;
    const int lhi = lane >> 4, llo = lane & 15;
    const int srow = lane >> 2;
    // phys chunk (lane&3) holds logical chunk (lane&3)^((srow>>1)&3)
    const int scol = (((lane & 3) ^ ((srow >> 1) & 3)) * 8);

    auto stage = [&](int k0, int buf) {
        #pragma unroll
        for (int p = 0; p < 2; p++) {
            int chunk = wave * 2 + p;                     // 0..7, 16 rows each
            int row = chunk * 16 + srow;
            gload16(A  + (size_t)(m0 + row) * 1024 + k0 + scol,
                    &As[buf][chunk * 512 + lane * 8]);
            gload16(Bm + (size_t)(n0 + row) * 1024 + k0 + scol,
                    &Bs[buf][chunk * 512 + lane * 8]);
        }
    };

    f4v acc[4][4] = {};
    int buf = 0;

    stage(0, 0);
    __syncthreads();                       // tile 0 staged (drains vmcnt)

    for (int k0 = 0; k0 < 1024; k0 += 32) {
        if (k0 + 32 < 1024) stage(k0 + 32, buf ^ 1);   // prefetch next slab

        // row = wr*64 + i*16 + llo -> (row>>1)&3 == (llo>>1)&3
        const int rch = (lhi ^ ((llo >> 1) & 3)) * 8;
        s8v a[4], b[4];
        #pragma unroll
        for (int i = 0; i < 4; i++)
            a[i] = *(const s8v*)&As[buf][(wr * 64 + i * 16 + llo) * 32 + rch];
        #pragma unroll
        for (int i = 0; i < 4; i++)
            b[i] = *(const s8v*)&Bs[buf][(wc * 64 + i * 16 + llo) * 32 + rch];
        #pragma unroll
        for (int i = 0; i < 4; i++)
            #pragma unroll
            for (int j = 0; j < 4; j++)
                acc[i][j] = __builtin_amdgcn_mfma_f32_16x16x32_bf16(a[i], b[j], acc[i][j], 0, 0, 0);

        __syncthreads();                   // buf consumed; prefetch landed
        buf ^= 1;
    }

    #pragma unroll
    for (int i = 0; i < 4; i++) {
        #pragma unroll
        for (int j = 0; j < 4; j++) {
            #pragma unroll
            for (int r = 0; r < 4; r++) {
                int m = m0 + wr * 64 + i * 16 + lhi * 4 + r;
                int n = n0 + wc * 64 + j * 16 + llo;
                if (MODE == 1) {
                    of[(size_t)m * 1024 + n] = acc[i][j][r];
                } else {
                    float val = acc[i][j][r];
                    int b  = m >> 11, t = m & 2047;
                    int which = n >> 10, hh = n & 1023;
                    int head = hh >> 6, d = hh & 63;
                    size_t bh = (size_t)(b * 16 + head);
                    if (which == 0)
                        // Q [b*T+t][h*64+d], pre-scaled by 1/sqrt(64)*log2(e)
                        o0[(size_t)m * 1024 + hh] = f2bf(val * 0.18033688011112042f);
                    else {
                        // K and V both t-major [b,h,t,d] (coalesced);
                        // V transposed+sigma-permuted later by transpose_v.
                        ushort_t* dst = (which == 1) ? o1 : o2;
                        dst[(bh * 2048 + t) * 64 + d] = f2bf(val);
                    }
                }
            }
        }
    }
}

// ---------------------------------------------------------------------------
// Flash attention, causal, exp2 domain, m-free softmax.
// Block: waves 0-3 -> q-tile p, waves 4-7 -> q-tile 15-p (32 rows/wave as
// 2 x 16-row groups). Shared KV loop of 32-2p tiles; K/V staged once for
// both q-tiles. KV tile 64 keys, double-buffered; 1 barrier/tile.
// K/V LDS: [64 rows][64 cols], 16B chunks XOR-swizzled by (row&7).
// P stored sigma-packed: col = llo*2+(c&1) per 32-half, matching sigma-
// permuted V^T; stores are ds_write_b32 of v_cvt_pk_bf16_f32 pairs.
// ---------------------------------------------------------------------------
__global__ __launch_bounds__(512, 4) void attn_kernel(
    const ushort_t* __restrict__ q_ws, const ushort_t* __restrict__ k_ws,
    const ushort_t* __restrict__ v_ws, ushort_t* __restrict__ ao_ws)
{
    const int p    = blockIdx.x;          // 0..7 -> q-tiles (p, 15-p)
    const int bh   = blockIdx.y;
    const int tid  = threadIdx.x;
    const int wave = tid >> 6, lane = tid & 63;
    const int lhi = lane >> 4, llo = lane & 15;
    const int b = bh >> 4, head = bh & 15;

    const ushort_t* Kb = k_ws + (size_t)bh * 2048 * 64;
    const ushort_t* Vb = v_ws + (size_t)bh * 64 * 2048;   // [d][sigma(t)]

    __shared__ __align__(16) ushort_t Ks [2][4096];       // [buf][64 kk][64 d] swz
    __shared__ __align__(16) ushort_t Vts[2][4096];       // [buf][64 d][64 sig] swz
    __shared__ __align__(16) ushort_t Ps [8][2][1280];    // [wave][g][half][16q][40]

    // stage tile t (64 keys, K+V) into buffer buf; 1 K + 1 V chunk per lane.
    const int srow = wave * 8 + (lane >> 3);              // 0..63
    const int gch  = ((lane & 7) ^ (srow & 7)) * 8;       // pre-swizzled src col
    auto stage = [&](int t, int buf) {
        const int kk0 = t * 64;
        gload16(Kb + (size_t)(kk0 + srow) * 64 + gch,
                &Ks[buf][srow * 64 + (lane & 7) * 8]);
        gload16(Vb + (size_t)srow * 2048 + kk0 + gch,
                &Vts[buf][srow * 64 + (lane & 7) * 8]);
    };

    const int qt  = (wave >> 2) ? (15 - p) : p;           // this wave's q-tile
    const int wq0 = qt * 128 + (wave & 3) * 32;           // wave's 32 q-rows

    s8v qf[2][2];
    #pragma unroll
    for (int g = 0; g < 2; g++) {
        const ushort_t* Qp = q_ws + (size_t)(b * 2048 + wq0 + g * 16 + llo) * 1024 + head * 64;
        qf[g][0] = *(const s8v*)(Qp + lhi * 8);
        qf[g][1] = *(const s8v*)(Qp + 32 + lhi * 8);
    }

    f4v o[2][4] = {};
    float lsum[2][4] = {};

    const int ntb = 32 - 2 * p;           // shared loop length (tile 15-p range)
    const int xs  = llo & 7;              // read-side XOR (row&7 == llo&7)
    int cur = 0;

    stage(0, 0);
    __syncthreads();                      // tile 0 staged (drains vmcnt)

    #pragma unroll 1
    for (int t = 0; t < ntb; t++) {
        if (t + 1 < ntb) stage(t + 1, cur ^ 1);   // prefetch next tile

        const int kk0 = t * 64;
        // kk0 multiple of 64, wq0 multiple of 32 => if any row unmasked,
        // BOTH 16-row groups have unmasked rows.
        if (kk0 <= wq0 + 31) {
            // ---- QK^T for both groups; kb frags transient per c ----
            f4v s0[4], s1[4];
            #pragma unroll
            for (int c = 0; c < 4; c++) {
                const int rb = (c * 16 + llo) * 64;
                s8v kb0 = *(const s8v*)&Ks[cur][rb + ((lhi    ) ^ xs) * 8];
                s8v kb1 = *(const s8v*)&Ks[cur][rb + ((4 + lhi) ^ xs) * 8];
                f4v z0 = {}, z1 = {};
                z0 = __builtin_amdgcn_mfma_f32_16x16x32_bf16(qf[0][0], kb0, z0, 0, 0, 0);
                z0 = __builtin_amdgcn_mfma_f32_16x16x32_bf16(qf[0][1], kb1, z0, 0, 0, 0);
                z1 = __builtin_amdgcn_mfma_f32_16x16x32_bf16(qf[1][0], kb0, z1, 0, 0, 0);
                z1 = __builtin_amdgcn_mfma_f32_16x16x32_bf16(qf[1][1], kb1, z1, 0, 0, 0);
                s0[c] = z0; s1[c] = z1;
            }

            // ---- m-free softmax + sigma-packed P store, per group ----
            #pragma unroll
            for (int g = 0; g < 2; g++) {
                const int qrb = wq0 + g * 16;
                f4v* s = g ? s1 : s0;
                if ((kk0 + 63) > qrb) {               // boundary: apply mask
                    #pragma unroll
                    for (int c = 0; c < 4; c++) {
                        int kkg = kk0 + c * 16 + llo;
                        #pragma unroll
                        for (int r = 0; r < 4; r++)
                            if (kkg > qrb + lhi * 4 + r) s[c][r] = -1e9f;
                    }
                }
                #pragma unroll
                for (int h = 0; h < 2; h++) {
                    #pragma unroll
                    for (int r = 0; r < 4; r++) {
                        float p0 = __builtin_amdgcn_exp2f(s[2 * h][r]);
                        float p1 = __builtin_amdgcn_exp2f(s[2 * h + 1][r]);
                        lsum[g][r] += p0 + p1;
                        unsigned pk;
                        asm("v_cvt_pk_bf16_f32 %0, %1, %2" : "=v"(pk) : "v"(p0), "v"(p1));
                        *(unsigned*)&Ps[wave][g][h * 640 + (lhi * 4 + r) * 40 + llo * 2] = pk;
                    }
                }
            }

            // ---- PV for both groups; vb frags transient per cd ----
            s8v pa[2][2];
            #pragma unroll
            for (int g = 0; g < 2; g++) {
                pa[g][0] = *(const s8v*)&Ps[wave][g][llo * 40 + lhi * 8];
                pa[g][1] = *(const s8v*)&Ps[wave][g][640 + llo * 40 + lhi * 8];
            }
            #pragma unroll
            for (int cd = 0; cd < 4; cd++) {
                const int rb = (cd * 16 + llo) * 64;
                s8v vb0 = *(const s8v*)&Vts[cur][rb + ((lhi    ) ^ xs) * 8];
                s8v vb1 = *(const s8v*)&Vts[cur][rb + ((4 + lhi) ^ xs) * 8];
                #pragma unroll
                for (int g = 0; g < 2; g++) {
                    o[g][cd] = __builtin_amdgcn_mfma_f32_16x16x32_bf16(pa[g][0], vb0, o[g][cd], 0, 0, 0);
                    o[g][cd] = __builtin_amdgcn_mfma_f32_16x16x32_bf16(pa[g][1], vb1, o[g][cd], 0, 0, 0);
                }
            }
        }

        __syncthreads();   // all waves done with buf cur; prefetch complete
        cur ^= 1;
    }

    // final l-sum reduction across the 16-lane llo group
    #pragma unroll
    for (int off = 1; off < 16; off <<= 1)
        #pragma unroll
        for (int g = 0; g < 2; g++)
            #pragma unroll
            for (int r = 0; r < 4; r++)
                lsum[g][r] += __shfl_xor(lsum[g][r], off, 64);

    #pragma unroll
    for (int g = 0; g < 2; g++)
        #pragma unroll
        for (int cd = 0; cd < 4; cd++)
            #pragma unroll
            for (int r = 0; r < 4; r++) {
                int qq = wq0 + g * 16 + lhi * 4 + r;
                int d  = cd * 16 + llo;
                ao_ws[((size_t)(b * 2048 + qq)) * 1024 + head * 64 + d] =
                    f2bf(o[g][cd][r] / lsum[g][r]);
            }
}

// ---------------------------------------------------------------------------
extern "C" void kernel_launch(void* const* d_in, const int* in_sizes, int n_in,
                              void* d_out, int out_size, void* d_ws, size_t ws_size,
                              hipStream_t stream) {
    const float* x    = (const float*)d_in[0];
    const float* wqkv = (const float*)d_in[1];
    const float* wout = (const float*)d_in[2];

    // ws (bf16 elems): wqkvb 3M | woutb 1M | xb 8M | q 8M | k 8M | vt 8M = 72 MB
    // reuse: v^T <- xb (dead after gemm0); ao <- vt (dead after transpose)
    ushort_t* wqkvb = (ushort_t*)d_ws;
    ushort_t* woutb = wqkvb + 3145728;
    ushort_t* xb    = woutb + 1048576;
    ushort_t* q_ws  = xb + 8388608;
    ushort_t* k_ws  = q_ws + 8388608;
    ushort_t* vt_ws = k_ws + 8388608;     // V t-major [b,h,t,d] from gemm0
    ushort_t* v_ws  = xb;                 // V^T [b,h,d,sigma(t)]
    ushort_t* ao_ws = vt_ws;              // attn output
    float*    out   = (float*)d_out;

    cast_f32_bf16<<<4096, 256, 0, stream>>>(x,    xb,    1048576);
    cast_f32_bf16<<<1536, 256, 0, stream>>>(wqkv, wqkvb, 393216);
    cast_f32_bf16<<< 512, 256, 0, stream>>>(wout, woutb, 131072);
    gemm_nt<0><<<dim3(64, 24), 256, 0, stream>>>(xb, wqkvb, q_ws, k_ws, vt_ws, nullptr);
    transpose_v<<<dim3(32, 64), 256, 0, stream>>>(vt_ws, v_ws);
    attn_kernel<<<dim3(8, 64), 512, 0, stream>>>(q_ws, k_ws, v_ws, ao_ws);
    gemm_nt<1><<<dim3(64, 8), 256, 0, stream>>>(ao_ws, woutb, nullptr, nullptr, nullptr, out);
}